// Round 10
// baseline (535.807 us; speedup 1.0000x reference)
//
#include <hip/hip_runtime.h>
#include <math.h>

#define NT 1024
#define CD 2
#define DD 1024
#define GG 16
#define LOG1E6 -13.8155105579642740f
#define NEG_BIG -1e30f

typedef short bf16x8 __attribute__((ext_vector_type(8)));
typedef float f32x4  __attribute__((ext_vector_type(4)));

__device__ __forceinline__ unsigned short bf16_rne(float x) {
    unsigned int u = __float_as_uint(x);
    unsigned int r = (u + 0x7fffu + ((u >> 16) & 1u)) >> 16;
    return (unsigned short)r;
}

// 3-way bf16 split of 8 fp32 values: x = h + m + l (24 mantissa bits kept).
__device__ __forceinline__ void split3_8(const float* v, bf16x8& h, bf16x8& m, bf16x8& l) {
    #pragma unroll
    for (int e = 0; e < 8; ++e) {
        const float x = v[e];
        const unsigned short hb = bf16_rne(x);
        const float hf = __uint_as_float((unsigned int)hb << 16);
        const float r1 = x - hf;
        const unsigned short mb = bf16_rne(r1);
        const float mf = __uint_as_float((unsigned int)mb << 16);
        const float r2 = r1 - mf;
        const unsigned short lb = bf16_rne(r2);
        h[e] = (short)hb; m[e] = (short)mb; l[e] = (short)lb;
    }
}

// ---------------------------------------------------------------------------
// K1: fp32 GEMM  P_z[r][e] = sum_d A[r][d] * W_z[e][d] + b_z[e]
//     tile 128 rows x 64 cols, BK=32, 256 threads, 8x4 micro-tile.
//     z in {Q,K}: writes EXACT 3-way bf16 splits (h/m/l) for k2a_mfma
//     (fp32 Q/K no longer stored - nothing reads them).  z==V: fp32 out.
// ---------------------------------------------------------------------------
__global__ __launch_bounds__(256) void k1_proj(
    const float* __restrict__ fa,
    const float* __restrict__ Wq, const float* __restrict__ bq,
    const float* __restrict__ Wk, const float* __restrict__ bk,
    const float* __restrict__ Wc, const float* __restrict__ bc,
    float* __restrict__ Vo,
    unsigned short* __restrict__ Qh, unsigned short* __restrict__ Qm, unsigned short* __restrict__ Ql,
    unsigned short* __restrict__ Kh, unsigned short* __restrict__ Km, unsigned short* __restrict__ Kl)
{
    const int et = blockIdx.x, rt = blockIdx.y, z = blockIdx.z;
    const float* W  = (z == 0) ? Wq : (z == 1) ? Wk : Wc;
    const float* bb = (z == 0) ? bq : (z == 1) ? bk : bc;
    unsigned short* Sh = (z == 0) ? Qh : Kh;
    unsigned short* Sm = (z == 0) ? Qm : Km;
    unsigned short* Sl = (z == 0) ? Ql : Kl;

    __shared__ float Al[32][132];
    __shared__ float Wl[32][68];

    const int t  = threadIdx.x;
    const int tx = t & 15, ty = t >> 4;
    const int dd = t & 7,  rr = t >> 3;
    const int r0 = rt * 128, e0 = et * 64;

    float acc[8][4];
    #pragma unroll
    for (int a = 0; a < 8; ++a)
        #pragma unroll
        for (int b = 0; b < 4; ++b) acc[a][b] = 0.f;

    for (int kt = 0; kt < 32; ++kt) {
        const int db = kt * 32 + dd * 4;
        #pragma unroll
        for (int p = 0; p < 4; ++p) {
            const int row = rr + p * 32;
            const int r = r0 + row;
            const int n = r & (NT - 1), c = r >> 10;
            float4 a4 = *(const float4*)&fa[((size_t)(n * CD + c)) * DD + db];
            Al[dd*4+0][row] = a4.x; Al[dd*4+1][row] = a4.y;
            Al[dd*4+2][row] = a4.z; Al[dd*4+3][row] = a4.w;
        }
        #pragma unroll
        for (int p = 0; p < 2; ++p) {
            const int erow = rr + p * 32;
            float4 w4 = *(const float4*)&W[((size_t)(e0 + erow)) * DD + db];
            Wl[dd*4+0][erow] = w4.x; Wl[dd*4+1][erow] = w4.y;
            Wl[dd*4+2][erow] = w4.z; Wl[dd*4+3][erow] = w4.w;
        }
        __syncthreads();
        #pragma unroll 4
        for (int d = 0; d < 32; ++d) {
            float4 a0 = *(const float4*)&Al[d][ty * 8];
            float4 a1 = *(const float4*)&Al[d][ty * 8 + 4];
            float4 w4 = *(const float4*)&Wl[d][tx * 4];
            float av[8] = {a0.x, a0.y, a0.z, a0.w, a1.x, a1.y, a1.z, a1.w};
            float wv[4] = {w4.x, w4.y, w4.z, w4.w};
            #pragma unroll
            for (int a = 0; a < 8; ++a)
                #pragma unroll
                for (int b = 0; b < 4; ++b) acc[a][b] += av[a] * wv[b];
        }
        __syncthreads();
    }
    float4 b4 = *(const float4*)&bb[e0 + tx * 4];
    #pragma unroll
    for (int a = 0; a < 8; ++a) {
        float o[4];
        o[0] = acc[a][0] + b4.x; o[1] = acc[a][1] + b4.y;
        o[2] = acc[a][2] + b4.z; o[3] = acc[a][3] + b4.w;
        const size_t idx = ((size_t)(r0 + ty * 8 + a)) * DD + e0 + tx * 4;
        if (z == 2) {
            *(float4*)&Vo[idx] = make_float4(o[0], o[1], o[2], o[3]);
        } else {
            ushort4 h4, m4, l4;
            unsigned short hv[4], mv[4], lv[4];
            #pragma unroll
            for (int q = 0; q < 4; ++q) {
                const float x = o[q];
                const unsigned short hb = bf16_rne(x);
                const float hf = __uint_as_float((unsigned int)hb << 16);
                const float r1 = x - hf;
                const unsigned short mb = bf16_rne(r1);
                const float mf = __uint_as_float((unsigned int)mb << 16);
                const unsigned short lb = bf16_rne(r1 - mf);
                hv[q] = hb; mv[q] = mb; lv[q] = lb;
            }
            h4.x = hv[0]; h4.y = hv[1]; h4.z = hv[2]; h4.w = hv[3];
            m4.x = mv[0]; m4.y = mv[1]; m4.z = mv[2]; m4.w = mv[3];
            l4.x = lv[0]; l4.y = lv[1]; l4.z = lv[2]; l4.w = lv[3];
            *(ushort4*)&Sh[idx] = h4;
            *(ushort4*)&Sm[idx] = m4;
            *(ushort4*)&Sl[idx] = l4;
        }
    }
}

// ---------------------------------------------------------------------------
// K2a v2: aff = Q.K^T/8 on the MATRIX pipe, 6-term 3-way split (R9-validated
//   error class ~1e-7, flip-safe).  One wave per (c,g,i-tile16,j-half512):
//   Q-frags register-resident (24 VGPR, loaded once); K-frags double-buffered
//   from global (L2-hot: 1.5MB slice shared by 64 waves).  No LDS.
//   MFMA C layout [m89]: row=(lane>>4)*4+q -> i, col=lane&15 -> j.
// ---------------------------------------------------------------------------
__global__ __launch_bounds__(256) void k2a_mfma(
    const unsigned short* __restrict__ Qh, const unsigned short* __restrict__ Qm,
    const unsigned short* __restrict__ Ql,
    const unsigned short* __restrict__ Kh, const unsigned short* __restrict__ Km,
    const unsigned short* __restrict__ Kl,
    float* __restrict__ aff)
{
    const int jh = blockIdx.x;           // 0..1 (512 j each)
    const int itg = blockIdx.y;          // 0..15 (4 i-tiles each)
    const int cg = blockIdx.z;           // 0..31
    const int c = cg >> 4, g = cg & 15;
    const int w = threadIdx.x >> 6, lane = threadIdx.x & 63;
    const int lg = lane & 15, lk = lane >> 4;
    const int i0 = (itg * 4 + w) * 16;

    // Q fragments (persistent)
    const size_t qb = ((size_t)(c * NT + i0 + lg)) * DD + g * 64 + lk * 8;
    bf16x8 qh[2], qm[2], ql[2];
    #pragma unroll
    for (int kp = 0; kp < 2; ++kp) {
        qh[kp] = *(const bf16x8*)&Qh[qb + kp * 32];
        qm[kp] = *(const bf16x8*)&Qm[qb + kp * 32];
        ql[kp] = *(const bf16x8*)&Ql[qb + kp * 32];
    }

    const size_t kb0 = ((size_t)(c * NT + jh * 512 + lg)) * DD + g * 64 + lk * 8;
    const size_t jstride = (size_t)16 * DD;

    // static double-buffer (no runtime-indexed vector arrays -> no scratch)
    bf16x8 kAh[2], kAm[2], kAl[2], kBh[2], kBm[2], kBl[2];
    #pragma unroll
    for (int kp = 0; kp < 2; ++kp) {
        kAh[kp] = *(const bf16x8*)&Kh[kb0 + kp * 32];
        kAm[kp] = *(const bf16x8*)&Km[kb0 + kp * 32];
        kAl[kp] = *(const bf16x8*)&Kl[kb0 + kp * 32];
    }

    const int j0base = jh * 512;
    #pragma unroll 1
    for (int jt = 0; jt < 32; jt += 2) {
        // prefetch jt+1 into B
        {
            const size_t kb = kb0 + (size_t)(jt + 1) * jstride;
            #pragma unroll
            for (int kp = 0; kp < 2; ++kp) {
                kBh[kp] = *(const bf16x8*)&Kh[kb + kp * 32];
                kBm[kp] = *(const bf16x8*)&Km[kb + kp * 32];
                kBl[kp] = *(const bf16x8*)&Kl[kb + kp * 32];
            }
        }
        // compute jt with A
        {
            f32x4 acc = {0.f, 0.f, 0.f, 0.f};
            #pragma unroll
            for (int kp = 0; kp < 2; ++kp) {
                acc = __builtin_amdgcn_mfma_f32_16x16x32_bf16(ql[kp], kAh[kp], acc, 0, 0, 0);
                acc = __builtin_amdgcn_mfma_f32_16x16x32_bf16(qh[kp], kAl[kp], acc, 0, 0, 0);
                acc = __builtin_amdgcn_mfma_f32_16x16x32_bf16(qm[kp], kAm[kp], acc, 0, 0, 0);
                acc = __builtin_amdgcn_mfma_f32_16x16x32_bf16(qm[kp], kAh[kp], acc, 0, 0, 0);
                acc = __builtin_amdgcn_mfma_f32_16x16x32_bf16(qh[kp], kAm[kp], acc, 0, 0, 0);
                acc = __builtin_amdgcn_mfma_f32_16x16x32_bf16(qh[kp], kAh[kp], acc, 0, 0, 0);
            }
            const int j0 = j0base + jt * 16;
            #pragma unroll
            for (int q = 0; q < 4; ++q)
                aff[((size_t)cg * NT + i0 + lk * 4 + q) * NT + j0 + lg] = acc[q] * 0.125f;
        }
        // prefetch jt+2 into A
        if (jt + 2 < 32) {
            const size_t kb = kb0 + (size_t)(jt + 2) * jstride;
            #pragma unroll
            for (int kp = 0; kp < 2; ++kp) {
                kAh[kp] = *(const bf16x8*)&Kh[kb + kp * 32];
                kAm[kp] = *(const bf16x8*)&Km[kb + kp * 32];
                kAl[kp] = *(const bf16x8*)&Kl[kb + kp * 32];
            }
        }
        // compute jt+1 with B
        {
            f32x4 acc = {0.f, 0.f, 0.f, 0.f};
            #pragma unroll
            for (int kp = 0; kp < 2; ++kp) {
                acc = __builtin_amdgcn_mfma_f32_16x16x32_bf16(ql[kp], kBh[kp], acc, 0, 0, 0);
                acc = __builtin_amdgcn_mfma_f32_16x16x32_bf16(qh[kp], kBl[kp], acc, 0, 0, 0);
                acc = __builtin_amdgcn_mfma_f32_16x16x32_bf16(qm[kp], kBm[kp], acc, 0, 0, 0);
                acc = __builtin_amdgcn_mfma_f32_16x16x32_bf16(qm[kp], kBh[kp], acc, 0, 0, 0);
                acc = __builtin_amdgcn_mfma_f32_16x16x32_bf16(qh[kp], kBm[kp], acc, 0, 0, 0);
                acc = __builtin_amdgcn_mfma_f32_16x16x32_bf16(qh[kp], kBh[kp], acc, 0, 0, 0);
            }
            const int j0 = j0base + (jt + 1) * 16;
            #pragma unroll
            for (int q = 0; q < 4; ++q)
                aff[((size_t)cg * NT + i0 + lk * 4 + q) * NT + j0 + lg] = acc[q] * 0.125f;
        }
    }
}

// ---------------------------------------------------------------------------
// K3 v4 (unchanged from R9): fused dense + top-10 scan; phase-G on MFMA.
// ---------------------------------------------------------------------------
__global__ __launch_bounds__(256, 4) void k3_scan(
    const float* __restrict__ pe, const float* __restrict__ iou,
    const float* __restrict__ WGw, const float* __restrict__ WGb,
    const float* __restrict__ aff,
    float* __restrict__ cv, int* __restrict__ ci)
{
    const int ch = blockIdx.x;   // 0..3
    const int it = blockIdx.y;   // 0..127
    const int c  = blockIdx.z;
    const int i0 = it * 8;

    __shared__ float wgl[8][16][33];   // [i][g][j(32)+1]
    __shared__ float ios[8][33];       // log_iou [i][j]

    const int t = threadIdx.x;
    const int wave = t >> 6, lane = t & 63;
    const int lg = lane & 15, lk = lane >> 4;
    const int p_i = t >> 5, jq = t & 31;
    const int s_i = t >> 5, s_g = (t >> 1) & 15, s_h = t & 1;

    bf16x8 bh[2], bm[2], bl[2];
    #pragma unroll
    for (int kp = 0; kp < 2; ++kp) {
        float w8[8];
        float4 w0 = *(const float4*)&WGw[lg * 64 + kp * 32 + lk * 8];
        float4 w1 = *(const float4*)&WGw[lg * 64 + kp * 32 + lk * 8 + 4];
        w8[0]=w0.x; w8[1]=w0.y; w8[2]=w0.z; w8[3]=w0.w;
        w8[4]=w1.x; w8[5]=w1.y; w8[6]=w1.z; w8[7]=w1.w;
        split3_8(w8, bh[kp], bm[kp], bl[kp]);
    }
    const float bias = WGb[lg];

    float tv[10]; int tidx[10];
    #pragma unroll
    for (int q = 0; q < 10; ++q) { tv[q] = NEG_BIG; tidx[q] = 0; }

    for (int s = 0; s < 8; ++s) {
        const int j0 = ch * 256 + s * 32;
        {
            const float ia = iou[((size_t)c * NT + (i0 + p_i)) * NT + j0 + jq];
            ios[p_i][jq] = (ia >= 1e-6f) ? 0.f : LOG1E6;
        }
        #pragma unroll 1
        for (int rtt = 0; rtt < 4; ++rtt) {
            const int rt = wave * 4 + rtt;
            const int ib = rt >> 1;
            const int jb = (rt & 1) * 16;
            const float* pr = &pe[(((size_t)c * NT + (i0 + ib)) * NT + (j0 + jb + lg)) * 64];
            f32x4 acc = {0.f, 0.f, 0.f, 0.f};
            #pragma unroll
            for (int kp = 0; kp < 2; ++kp) {
                float a8[8];
                float4 v0 = *(const float4*)&pr[kp * 32 + lk * 8];
                float4 v1 = *(const float4*)&pr[kp * 32 + lk * 8 + 4];
                a8[0]=v0.x; a8[1]=v0.y; a8[2]=v0.z; a8[3]=v0.w;
                a8[4]=v1.x; a8[5]=v1.y; a8[6]=v1.z; a8[7]=v1.w;
                bf16x8 ah, am, al;
                split3_8(a8, ah, am, al);
                acc = __builtin_amdgcn_mfma_f32_16x16x32_bf16(al, bh[kp], acc, 0, 0, 0);
                acc = __builtin_amdgcn_mfma_f32_16x16x32_bf16(ah, bl[kp], acc, 0, 0, 0);
                acc = __builtin_amdgcn_mfma_f32_16x16x32_bf16(am, bm[kp], acc, 0, 0, 0);
                acc = __builtin_amdgcn_mfma_f32_16x16x32_bf16(am, bh[kp], acc, 0, 0, 0);
                acc = __builtin_amdgcn_mfma_f32_16x16x32_bf16(ah, bm[kp], acc, 0, 0, 0);
                acc = __builtin_amdgcn_mfma_f32_16x16x32_bf16(ah, bh[kp], acc, 0, 0, 0);
            }
            #pragma unroll
            for (int q = 0; q < 4; ++q) {
                const float v = acc[q] + bias;
                wgl[ib][lg][jb + lk * 4 + q] = (v > 1e-6f) ? __logf(v) : LOG1E6;
            }
        }
        __syncthreads();
        {
            const float* ar = &aff[(((size_t)(c * GG + s_g)) * NT + (i0 + s_i)) * NT + j0 + s_h * 16];
            const float* wl = &wgl[s_i][s_g][s_h * 16];
            const float* il = &ios[s_i][s_h * 16];
            #pragma unroll
            for (int j4 = 0; j4 < 16; j4 += 4) {
                float4 a4 = *(const float4*)&ar[j4];
                float av[4] = {a4.x, a4.y, a4.z, a4.w};
                #pragma unroll
                for (int q = 0; q < 4; ++q) {
                    const float val = wl[j4 + q] + av[q] + il[j4 + q];
                    if (val > tv[0]) {
                        const int ix = j0 + s_h * 16 + j4 + q;
                        #pragma unroll
                        for (int sl = 0; sl < 10; ++sl) {
                            const bool up   = (sl < 9) ? (val > tv[sl + 1]) : false;
                            const bool here = (val > tv[sl]);
                            const float ntv = up ? tv[sl + 1] : (here ? val : tv[sl]);
                            const int   nti = up ? tidx[sl + 1] : (here ? ix : tidx[sl]);
                            tv[sl] = ntv; tidx[sl] = nti;
                        }
                    }
                }
            }
        }
        __syncthreads();
    }

    float* mv = &wgl[0][0][0];
    int*   mi = (int*)(mv + 1280);
    const int pair = t >> 1;
    if (s_h == 1) {
        #pragma unroll
        for (int q = 0; q < 10; ++q) { mv[pair * 10 + q] = tv[q]; mi[pair * 10 + q] = tidx[q]; }
    }
    __syncthreads();
    if (s_h == 0) {
        for (int q = 9; q >= 0; --q) {
            const float val = mv[pair * 10 + q];
            const int   ix  = mi[pair * 10 + q];
            if (val > tv[0]) {
                #pragma unroll
                for (int sl = 0; sl < 10; ++sl) {
                    const bool up   = (sl < 9) ? (val > tv[sl + 1]) : false;
                    const bool here = (val > tv[sl]);
                    const float ntv = up ? tv[sl + 1] : (here ? val : tv[sl]);
                    const int   nti = up ? tidx[sl + 1] : (here ? ix : tidx[sl]);
                    tv[sl] = ntv; tidx[sl] = nti;
                }
            }
        }
        const size_t base = ((((size_t)c * NT + (i0 + s_i)) * GG + s_g) * 4 + ch) * 10;
        #pragma unroll
        for (int q = 0; q < 10; ++q) { cv[base + q] = tv[q]; ci[base + q] = tidx[q]; }
    }
}

// ---------------------------------------------------------------------------
// K2b2 (unchanged): per-(c,i,g) wave merge + softmax + coalesced V-gather.
// ---------------------------------------------------------------------------
__global__ __launch_bounds__(256) void k2b2_fin(
    const float* __restrict__ cv, const int* __restrict__ ci,
    const float* __restrict__ V, float* __restrict__ y)
{
    const int w    = (blockIdx.x << 2) + (threadIdx.x >> 6);
    const int lane = threadIdx.x & 63;
    const int c = w >> 14;
    const int i = (w >> 4) & (NT - 1);
    const int g = w & 15;

    float tv[10]; int tidx[10];
    #pragma unroll
    for (int q = 0; q < 10; ++q) { tv[q] = NEG_BIG; tidx[q] = 0; }

    const size_t base = (size_t)w * 40;
    for (int chn = 0; chn < 4; ++chn) {
        const float* cvp = &cv[base + chn * 10];
        const int*   cip = &ci[base + chn * 10];
        for (int q = 9; q >= 0; --q) {
            const float val = cvp[q];
            const int   ix  = cip[q];
            if (val > tv[0]) {
                #pragma unroll
                for (int sl = 0; sl < 10; ++sl) {
                    const bool up   = (sl < 9) ? (val > tv[sl + 1]) : false;
                    const bool here = (val > tv[sl]);
                    const float ntv = up ? tv[sl + 1] : (here ? val : tv[sl]);
                    const int   nti = up ? tidx[sl + 1] : (here ? ix : tidx[sl]);
                    tv[sl] = ntv; tidx[sl] = nti;
                }
            }
        }
    }
    const float m = tv[9];
    float wgt[10]; float sm = 0.f;
    #pragma unroll
    for (int q = 0; q < 10; ++q) { wgt[q] = __expf(tv[q] - m); sm += wgt[q]; }
    const float inv = 1.f / sm;
    float o = 0.f;
    #pragma unroll
    for (int q = 0; q < 10; ++q)
        o += (wgt[q] * inv) * V[((size_t)(c * NT + tidx[q])) * DD + g * 64 + lane];
    y[((size_t)i * CD + c) * DD + g * 64 + lane] = o;
}

extern "C" void kernel_launch(void* const* d_in, const int* in_sizes, int n_in,
                              void* d_out, int out_size, void* d_ws, size_t ws_size,
                              hipStream_t stream) {
    (void)in_sizes; (void)n_in; (void)out_size; (void)ws_size;
    const float* f_a = (const float*)d_in[0];
    const float* pe  = (const float*)d_in[1];
    const float* iou = (const float*)d_in[2];
    const float* WGw = (const float*)d_in[3];
    const float* WGb = (const float*)d_in[4];
    const float* WKw = (const float*)d_in[5];
    const float* WKb = (const float*)d_in[6];
    const float* WQw = (const float*)d_in[7];
    const float* WQb = (const float*)d_in[8];
    const float* Cw  = (const float*)d_in[9];
    const float* Cb  = (const float*)d_in[10];
    float* yout = (float*)d_out;

    // ws floats: [0..2^21) cv overlay | [2^21..2^22) ci overlay | V [2^22..]
    //   | aff at 3*2^21, 2^25 floats | bf16 split arrays after aff (24MB).
    float* ws  = (float*)d_ws;
    float* V   = ws + (2u << 21);
    float* aff = ws + (3u << 21);
    float* cv  = ws;
    int*   ci  = (int*)(ws + (1u << 21));
    unsigned short* sp = (unsigned short*)(ws + (3u << 21) + (1u << 25));
    const size_t SPN = (size_t)CD * NT * DD;   // 2M elements per array
    unsigned short* Qh = sp;
    unsigned short* Qm = sp + SPN;
    unsigned short* Ql = sp + 2 * SPN;
    unsigned short* Kh = sp + 3 * SPN;
    unsigned short* Km = sp + 4 * SPN;
    unsigned short* Kl = sp + 5 * SPN;

    k1_proj<<<dim3(16, 16, 3), 256, 0, stream>>>(f_a, WQw, WQb, WKw, WKb, Cw, Cb,
                                                 V, Qh, Qm, Ql, Kh, Km, Kl);
    k2a_mfma<<<dim3(2, 16, 32), 256, 0, stream>>>(Qh, Qm, Ql, Kh, Km, Kl, aff);
    k3_scan<<<dim3(4, 128, 2), 256, 0, stream>>>(pe, iou, WGw, WGb, aff, cv, ci);
    k2b2_fin<<<8192, 256, 0, stream>>>(cv, ci, V, yout);
}

// Round 11
// 426.304 us; speedup vs baseline: 1.2569x; 1.2569x over previous
//
#include <hip/hip_runtime.h>
#include <math.h>

#define NT 1024
#define CD 2
#define DD 1024
#define GG 16
#define LOG1E6 -13.8155105579642740f
#define NEG_BIG -1e30f

typedef short bf16x8 __attribute__((ext_vector_type(8)));
typedef float f32x4  __attribute__((ext_vector_type(4)));

__device__ __forceinline__ unsigned short bf16_rne(float x) {
    unsigned int u = __float_as_uint(x);
    unsigned int r = (u + 0x7fffu + ((u >> 16) & 1u)) >> 16;
    return (unsigned short)r;
}

__device__ __forceinline__ void split3_8(const float* v, bf16x8& h, bf16x8& m, bf16x8& l) {
    #pragma unroll
    for (int e = 0; e < 8; ++e) {
        const float x = v[e];
        const unsigned short hb = bf16_rne(x);
        const float hf = __uint_as_float((unsigned int)hb << 16);
        const float r1 = x - hf;
        const unsigned short mb = bf16_rne(r1);
        const float mf = __uint_as_float((unsigned int)mb << 16);
        const float r2 = r1 - mf;
        const unsigned short lb = bf16_rne(r2);
        h[e] = (short)hb; m[e] = (short)mb; l[e] = (short)lb;
    }
}

// ---------------------------------------------------------------------------
// K0: pre-split fa / Wq / Wk / Wc into exact 3-way bf16 (h+m+l) arrays.
//   One pass; each element split exactly once (k1 staging then does pure
//   copies - no conversion VALU in the GEMM hot loop).
//   region (blockIdx.y): 0=fa (2M el), 1=Wq, 2=Wk, 3=Wc (1M el each).
// ---------------------------------------------------------------------------
__global__ __launch_bounds__(256) void k0_split(
    const float* __restrict__ fa, const float* __restrict__ Wq,
    const float* __restrict__ Wk, const float* __restrict__ Wc,
    unsigned short* __restrict__ Fh, unsigned short* __restrict__ Fm, unsigned short* __restrict__ Fl,
    unsigned short* __restrict__ WQh, unsigned short* __restrict__ WQm, unsigned short* __restrict__ WQl,
    unsigned short* __restrict__ WKh, unsigned short* __restrict__ WKm, unsigned short* __restrict__ WKl,
    unsigned short* __restrict__ WCh, unsigned short* __restrict__ WCm, unsigned short* __restrict__ WCl)
{
    const int reg = blockIdx.y;
    const float* src = (reg == 0) ? fa : (reg == 1) ? Wq : (reg == 2) ? Wk : Wc;
    unsigned short* dh = (reg == 0) ? Fh : (reg == 1) ? WQh : (reg == 2) ? WKh : WCh;
    unsigned short* dm = (reg == 0) ? Fm : (reg == 1) ? WQm : (reg == 2) ? WKm : WCm;
    unsigned short* dl = (reg == 0) ? Fl : (reg == 1) ? WQl : (reg == 2) ? WKl : WCl;
    const int nv = (reg == 0) ? (1 << 19) : (1 << 18);   // float4 count

    for (int v = blockIdx.x * 256 + threadIdx.x; v < nv; v += gridDim.x * 256) {
        float4 x4 = *(const float4*)&src[(size_t)v * 4];
        float xv[4] = {x4.x, x4.y, x4.z, x4.w};
        ushort4 h4, m4, l4;
        unsigned short hv[4], mv[4], lv[4];
        #pragma unroll
        for (int q = 0; q < 4; ++q) {
            const float x = xv[q];
            const unsigned short hb = bf16_rne(x);
            const float hf = __uint_as_float((unsigned int)hb << 16);
            const float r1 = x - hf;
            const unsigned short mb = bf16_rne(r1);
            const float mf = __uint_as_float((unsigned int)mb << 16);
            const unsigned short lb = bf16_rne(r1 - mf);
            hv[q] = hb; mv[q] = mb; lv[q] = lb;
        }
        h4.x = hv[0]; h4.y = hv[1]; h4.z = hv[2]; h4.w = hv[3];
        m4.x = mv[0]; m4.y = mv[1]; m4.z = mv[2]; m4.w = mv[3];
        l4.x = lv[0]; l4.y = lv[1]; l4.z = lv[2]; l4.w = lv[3];
        *(ushort4*)&dh[(size_t)v * 4] = h4;
        *(ushort4*)&dm[(size_t)v * 4] = m4;
        *(ushort4*)&dl[(size_t)v * 4] = l4;
    }
}

// ---------------------------------------------------------------------------
// K1 v2: MFMA GEMM  Out[r][e] = sum_d A[r][d]*W[e][d] + b[e]  (fp32 out)
//   6-term 3-way-split bf16 MFMA (order = R9/R10-validated, ~1e-7 rel).
//   Operands pre-split by k0 -> staging is pure uint4 copies (no VALU).
//   Tile 128r x 64e, BK=32, 4 waves (2x2): wave = 64r x 32e = 4x2 frags
//   (8 independent acc chains - R10's single-chain mistake avoided).
//   LDS 41.5KB -> 3 blocks/CU.  A row r=(c,n): fa[(n*CD+c)*DD].
// ---------------------------------------------------------------------------
__global__ __launch_bounds__(256) void k1_mfma(
    const unsigned short* __restrict__ Fh, const unsigned short* __restrict__ Fm,
    const unsigned short* __restrict__ Fl,
    const unsigned short* __restrict__ WQh, const unsigned short* __restrict__ WQm,
    const unsigned short* __restrict__ WQl,
    const unsigned short* __restrict__ WKh, const unsigned short* __restrict__ WKm,
    const unsigned short* __restrict__ WKl,
    const unsigned short* __restrict__ WCh, const unsigned short* __restrict__ WCm,
    const unsigned short* __restrict__ WCl,
    const float* __restrict__ bq, const float* __restrict__ bk, const float* __restrict__ bc,
    float* __restrict__ Qo, float* __restrict__ Ko, float* __restrict__ Vo)
{
    const int et = blockIdx.x, rt = blockIdx.y, z = blockIdx.z;
    const unsigned short* Wh = (z == 0) ? WQh : (z == 1) ? WKh : WCh;
    const unsigned short* Wm = (z == 0) ? WQm : (z == 1) ? WKm : WCm;
    const unsigned short* Wl = (z == 0) ? WQl : (z == 1) ? WKl : WCl;
    const float* bb = (z == 0) ? bq : (z == 1) ? bk : bc;
    float* Out      = (z == 0) ? Qo : (z == 1) ? Ko : Vo;

    const int c  = rt >> 3;
    const int n0 = (rt & 7) * 128;
    const int r0 = rt * 128;
    const int e0 = et * 64;

    // [row][k(32)+pad4] ushort: row stride 72B -> 2-way banks on b128 frags
    __shared__ unsigned short Ah[128][36], Am[128][36], Al[128][36];
    __shared__ unsigned short Bh[64][36],  Bm[64][36],  Bl[64][36];

    const int t    = threadIdx.x;
    const int wave = t >> 6, lane = t & 63;
    const int wr   = wave >> 1, wc = wave & 1;
    const int lrow = lane & 15, lk = lane >> 4;

    f32x4 acc[4][2];
    #pragma unroll
    for (int m = 0; m < 4; ++m)
        #pragma unroll
        for (int n = 0; n < 2; ++n) acc[m][n] = (f32x4){0.f, 0.f, 0.f, 0.f};

    for (int kt = 0; kt < 32; ++kt) {
        const int kb = kt * 32;
        // stage A: tasks t, t+256 -> (row = task>>2, seg = task&3), 8 el each
        #pragma unroll
        for (int p = 0; p < 2; ++p) {
            const int task = t + p * 256;
            const int row = task >> 2, seg = task & 3;
            const size_t gs = ((size_t)((n0 + row) * CD + c)) * DD + kb + seg * 8;
            *(uint4*)&Ah[row][seg * 8] = *(const uint4*)&Fh[gs];
            *(uint4*)&Am[row][seg * 8] = *(const uint4*)&Fm[gs];
            *(uint4*)&Al[row][seg * 8] = *(const uint4*)&Fl[gs];
        }
        // stage W: 64 rows x 4 segs = 256 tasks
        {
            const int row = t >> 2, seg = t & 3;
            const size_t gs = ((size_t)(e0 + row)) * DD + kb + seg * 8;
            *(uint4*)&Bh[row][seg * 8] = *(const uint4*)&Wh[gs];
            *(uint4*)&Bm[row][seg * 8] = *(const uint4*)&Wm[gs];
            *(uint4*)&Bl[row][seg * 8] = *(const uint4*)&Wl[gs];
        }
        __syncthreads();
        {
            bf16x8 ah[4], am[4], al[4], bh[2], bm[2], bl[2];
            #pragma unroll
            for (int m = 0; m < 4; ++m) {
                const int row = wr * 64 + m * 16 + lrow;
                ah[m] = *(const bf16x8*)&Ah[row][lk * 8];
                am[m] = *(const bf16x8*)&Am[row][lk * 8];
                al[m] = *(const bf16x8*)&Al[row][lk * 8];
            }
            #pragma unroll
            for (int n = 0; n < 2; ++n) {
                const int row = wc * 32 + n * 16 + lrow;
                bh[n] = *(const bf16x8*)&Bh[row][lk * 8];
                bm[n] = *(const bf16x8*)&Bm[row][lk * 8];
                bl[n] = *(const bf16x8*)&Bl[row][lk * 8];
            }
            #pragma unroll
            for (int m = 0; m < 4; ++m)
                #pragma unroll
                for (int n = 0; n < 2; ++n) {
                    acc[m][n] = __builtin_amdgcn_mfma_f32_16x16x32_bf16(al[m], bh[n], acc[m][n], 0, 0, 0);
                    acc[m][n] = __builtin_amdgcn_mfma_f32_16x16x32_bf16(ah[m], bl[n], acc[m][n], 0, 0, 0);
                    acc[m][n] = __builtin_amdgcn_mfma_f32_16x16x32_bf16(am[m], bm[n], acc[m][n], 0, 0, 0);
                    acc[m][n] = __builtin_amdgcn_mfma_f32_16x16x32_bf16(am[m], bh[n], acc[m][n], 0, 0, 0);
                    acc[m][n] = __builtin_amdgcn_mfma_f32_16x16x32_bf16(ah[m], bm[n], acc[m][n], 0, 0, 0);
                    acc[m][n] = __builtin_amdgcn_mfma_f32_16x16x32_bf16(ah[m], bh[n], acc[m][n], 0, 0, 0);
                }
        }
        __syncthreads();
    }
    // epilogue: C frag row=(lk*4+q) -> output row; col=lrow -> e  [m89]
    #pragma unroll
    for (int n = 0; n < 2; ++n) {
        const int e = e0 + wc * 32 + n * 16 + lrow;
        const float bias = bb[e];
        #pragma unroll
        for (int m = 0; m < 4; ++m) {
            const int r = r0 + wr * 64 + m * 16 + lk * 4;
            #pragma unroll
            for (int q = 0; q < 4; ++q)
                Out[((size_t)(r + q)) * DD + e] = acc[m][n][q] + bias;
        }
    }
}

// ---------------------------------------------------------------------------
// K2a (fp32, R6-R9 validated): aff = Q.K^T / 8
// ---------------------------------------------------------------------------
__global__ __launch_bounds__(256) void k2a_aff(
    const float* __restrict__ Q, const float* __restrict__ Km,
    float* __restrict__ aff)
{
    const int jt = blockIdx.x, it = blockIdx.y, cg = blockIdx.z;
    const int c = cg >> 4, g = cg & 15;
    __shared__ float Ql[64][68];
    __shared__ float Kl[64][68];
    const int t = threadIdx.x;
    const int dd = t & 15, rr = t >> 4;
    const int i0 = it * 64, j0 = jt * 64;
    #pragma unroll
    for (int p = 0; p < 4; ++p) {
        const int row = rr + p * 16;
        float4 q4 = *(const float4*)&Q[((size_t)(c * NT + i0 + row)) * DD + g * 64 + dd * 4];
        Ql[dd*4+0][row] = q4.x; Ql[dd*4+1][row] = q4.y;
        Ql[dd*4+2][row] = q4.z; Ql[dd*4+3][row] = q4.w;
        float4 k4 = *(const float4*)&Km[((size_t)(c * NT + j0 + row)) * DD + g * 64 + dd * 4];
        Kl[dd*4+0][row] = k4.x; Kl[dd*4+1][row] = k4.y;
        Kl[dd*4+2][row] = k4.z; Kl[dd*4+3][row] = k4.w;
    }
    __syncthreads();
    const int tx = t & 15, ty = t >> 4;
    float acc[4][4];
    #pragma unroll
    for (int a = 0; a < 4; ++a)
        #pragma unroll
        for (int b = 0; b < 4; ++b) acc[a][b] = 0.f;
    #pragma unroll 8
    for (int d = 0; d < 64; ++d) {
        float4 q4 = *(const float4*)&Ql[d][ty * 4];
        float4 k4 = *(const float4*)&Kl[d][tx * 4];
        float qv[4] = {q4.x, q4.y, q4.z, q4.w};
        float kv[4] = {k4.x, k4.y, k4.z, k4.w};
        #pragma unroll
        for (int a = 0; a < 4; ++a)
            #pragma unroll
            for (int b = 0; b < 4; ++b) acc[a][b] += qv[a] * kv[b];
    }
    #pragma unroll
    for (int a = 0; a < 4; ++a) {
        float4 o;
        o.x = acc[a][0] * 0.125f; o.y = acc[a][1] * 0.125f;
        o.z = acc[a][2] * 0.125f; o.w = acc[a][3] * 0.125f;
        *(float4*)&aff[(((size_t)(c * GG + g)) * NT + i0 + ty * 4 + a) * NT + j0 + tx * 4] = o;
    }
}

// ---------------------------------------------------------------------------
// K3 (unchanged from R9): fused dense + top-10 scan; phase-G on MFMA.
// ---------------------------------------------------------------------------
__global__ __launch_bounds__(256, 4) void k3_scan(
    const float* __restrict__ pe, const float* __restrict__ iou,
    const float* __restrict__ WGw, const float* __restrict__ WGb,
    const float* __restrict__ aff,
    float* __restrict__ cv, int* __restrict__ ci)
{
    const int ch = blockIdx.x;
    const int it = blockIdx.y;
    const int c  = blockIdx.z;
    const int i0 = it * 8;

    __shared__ float wgl[8][16][33];
    __shared__ float ios[8][33];

    const int t = threadIdx.x;
    const int wave = t >> 6, lane = t & 63;
    const int lg = lane & 15, lk = lane >> 4;
    const int p_i = t >> 5, jq = t & 31;
    const int s_i = t >> 5, s_g = (t >> 1) & 15, s_h = t & 1;

    bf16x8 bh[2], bm[2], bl[2];
    #pragma unroll
    for (int kp = 0; kp < 2; ++kp) {
        float w8[8];
        float4 w0 = *(const float4*)&WGw[lg * 64 + kp * 32 + lk * 8];
        float4 w1 = *(const float4*)&WGw[lg * 64 + kp * 32 + lk * 8 + 4];
        w8[0]=w0.x; w8[1]=w0.y; w8[2]=w0.z; w8[3]=w0.w;
        w8[4]=w1.x; w8[5]=w1.y; w8[6]=w1.z; w8[7]=w1.w;
        split3_8(w8, bh[kp], bm[kp], bl[kp]);
    }
    const float bias = WGb[lg];

    float tv[10]; int tidx[10];
    #pragma unroll
    for (int q = 0; q < 10; ++q) { tv[q] = NEG_BIG; tidx[q] = 0; }

    for (int s = 0; s < 8; ++s) {
        const int j0 = ch * 256 + s * 32;
        {
            const float ia = iou[((size_t)c * NT + (i0 + p_i)) * NT + j0 + jq];
            ios[p_i][jq] = (ia >= 1e-6f) ? 0.f : LOG1E6;
        }
        #pragma unroll 1
        for (int rtt = 0; rtt < 4; ++rtt) {
            const int rt = wave * 4 + rtt;
            const int ib = rt >> 1;
            const int jb = (rt & 1) * 16;
            const float* pr = &pe[(((size_t)c * NT + (i0 + ib)) * NT + (j0 + jb + lg)) * 64];
            f32x4 acc = {0.f, 0.f, 0.f, 0.f};
            #pragma unroll
            for (int kp = 0; kp < 2; ++kp) {
                float a8[8];
                float4 v0 = *(const float4*)&pr[kp * 32 + lk * 8];
                float4 v1 = *(const float4*)&pr[kp * 32 + lk * 8 + 4];
                a8[0]=v0.x; a8[1]=v0.y; a8[2]=v0.z; a8[3]=v0.w;
                a8[4]=v1.x; a8[5]=v1.y; a8[6]=v1.z; a8[7]=v1.w;
                bf16x8 ah, am, al;
                split3_8(a8, ah, am, al);
                acc = __builtin_amdgcn_mfma_f32_16x16x32_bf16(al, bh[kp], acc, 0, 0, 0);
                acc = __builtin_amdgcn_mfma_f32_16x16x32_bf16(ah, bl[kp], acc, 0, 0, 0);
                acc = __builtin_amdgcn_mfma_f32_16x16x32_bf16(am, bm[kp], acc, 0, 0, 0);
                acc = __builtin_amdgcn_mfma_f32_16x16x32_bf16(am, bh[kp], acc, 0, 0, 0);
                acc = __builtin_amdgcn_mfma_f32_16x16x32_bf16(ah, bm[kp], acc, 0, 0, 0);
                acc = __builtin_amdgcn_mfma_f32_16x16x32_bf16(ah, bh[kp], acc, 0, 0, 0);
            }
            #pragma unroll
            for (int q = 0; q < 4; ++q) {
                const float v = acc[q] + bias;
                wgl[ib][lg][jb + lk * 4 + q] = (v > 1e-6f) ? __logf(v) : LOG1E6;
            }
        }
        __syncthreads();
        {
            const float* ar = &aff[(((size_t)(c * GG + s_g)) * NT + (i0 + s_i)) * NT + j0 + s_h * 16];
            const float* wl = &wgl[s_i][s_g][s_h * 16];
            const float* il = &ios[s_i][s_h * 16];
            #pragma unroll
            for (int j4 = 0; j4 < 16; j4 += 4) {
                float4 a4 = *(const float4*)&ar[j4];
                float av[4] = {a4.x, a4.y, a4.z, a4.w};
                #pragma unroll
                for (int q = 0; q < 4; ++q) {
                    const float val = wl[j4 + q] + av[q] + il[j4 + q];
                    if (val > tv[0]) {
                        const int ix = j0 + s_h * 16 + j4 + q;
                        #pragma unroll
                        for (int sl = 0; sl < 10; ++sl) {
                            const bool up   = (sl < 9) ? (val > tv[sl + 1]) : false;
                            const bool here = (val > tv[sl]);
                            const float ntv = up ? tv[sl + 1] : (here ? val : tv[sl]);
                            const int   nti = up ? tidx[sl + 1] : (here ? ix : tidx[sl]);
                            tv[sl] = ntv; tidx[sl] = nti;
                        }
                    }
                }
            }
        }
        __syncthreads();
    }

    float* mv = &wgl[0][0][0];
    int*   mi = (int*)(mv + 1280);
    const int pair = t >> 1;
    if (s_h == 1) {
        #pragma unroll
        for (int q = 0; q < 10; ++q) { mv[pair * 10 + q] = tv[q]; mi[pair * 10 + q] = tidx[q]; }
    }
    __syncthreads();
    if (s_h == 0) {
        for (int q = 9; q >= 0; --q) {
            const float val = mv[pair * 10 + q];
            const int   ix  = mi[pair * 10 + q];
            if (val > tv[0]) {
                #pragma unroll
                for (int sl = 0; sl < 10; ++sl) {
                    const bool up   = (sl < 9) ? (val > tv[sl + 1]) : false;
                    const bool here = (val > tv[sl]);
                    const float ntv = up ? tv[sl + 1] : (here ? val : tv[sl]);
                    const int   nti = up ? tidx[sl + 1] : (here ? ix : tidx[sl]);
                    tv[sl] = ntv; tidx[sl] = nti;
                }
            }
        }
        const size_t base = ((((size_t)c * NT + (i0 + s_i)) * GG + s_g) * 4 + ch) * 10;
        #pragma unroll
        for (int q = 0; q < 10; ++q) { cv[base + q] = tv[q]; ci[base + q] = tidx[q]; }
    }
}

// ---------------------------------------------------------------------------
// K2b2 (unchanged): per-(c,i,g) wave merge + softmax + coalesced V-gather.
// ---------------------------------------------------------------------------
__global__ __launch_bounds__(256) void k2b2_fin(
    const float* __restrict__ cv, const int* __restrict__ ci,
    const float* __restrict__ V, float* __restrict__ y)
{
    const int w    = (blockIdx.x << 2) + (threadIdx.x >> 6);
    const int lane = threadIdx.x & 63;
    const int c = w >> 14;
    const int i = (w >> 4) & (NT - 1);
    const int g = w & 15;

    float tv[10]; int tidx[10];
    #pragma unroll
    for (int q = 0; q < 10; ++q) { tv[q] = NEG_BIG; tidx[q] = 0; }

    const size_t base = (size_t)w * 40;
    for (int chn = 0; chn < 4; ++chn) {
        const float* cvp = &cv[base + chn * 10];
        const int*   cip = &ci[base + chn * 10];
        for (int q = 9; q >= 0; --q) {
            const float val = cvp[q];
            const int   ix  = cip[q];
            if (val > tv[0]) {
                #pragma unroll
                for (int sl = 0; sl < 10; ++sl) {
                    const bool up   = (sl < 9) ? (val > tv[sl + 1]) : false;
                    const bool here = (val > tv[sl]);
                    const float ntv = up ? tv[sl + 1] : (here ? val : tv[sl]);
                    const int   nti = up ? tidx[sl + 1] : (here ? ix : tidx[sl]);
                    tv[sl] = ntv; tidx[sl] = nti;
                }
            }
        }
    }
    const float m = tv[9];
    float wgt[10]; float sm = 0.f;
    #pragma unroll
    for (int q = 0; q < 10; ++q) { wgt[q] = __expf(tv[q] - m); sm += wgt[q]; }
    const float inv = 1.f / sm;
    float o = 0.f;
    #pragma unroll
    for (int q = 0; q < 10; ++q)
        o += (wgt[q] * inv) * V[((size_t)(c * NT + tidx[q])) * DD + g * 64 + lane];
    y[((size_t)i * CD + c) * DD + g * 64 + lane] = o;
}

extern "C" void kernel_launch(void* const* d_in, const int* in_sizes, int n_in,
                              void* d_out, int out_size, void* d_ws, size_t ws_size,
                              hipStream_t stream) {
    (void)in_sizes; (void)n_in; (void)out_size; (void)ws_size;
    const float* f_a = (const float*)d_in[0];
    const float* pe  = (const float*)d_in[1];
    const float* iou = (const float*)d_in[2];
    const float* WGw = (const float*)d_in[3];
    const float* WGb = (const float*)d_in[4];
    const float* WKw = (const float*)d_in[5];
    const float* WKb = (const float*)d_in[6];
    const float* WQw = (const float*)d_in[7];
    const float* WQb = (const float*)d_in[8];
    const float* Cw  = (const float*)d_in[9];
    const float* Cb  = (const float*)d_in[10];
    float* yout = (float*)d_out;

    // ws floats: Q [2^21] | K [2^21] | V [2^21] | aff [2^25] | split arrays.
    // cv overlays Q, ci overlays K (dead after k2a).
    float* ws  = (float*)d_ws;
    float* Q   = ws;
    float* Kp  = ws + (1u << 21);
    float* V   = ws + (2u << 21);
    float* aff = ws + (3u << 21);
    float* cv  = ws;
    int*   ci  = (int*)(ws + (1u << 21));
    unsigned short* sp = (unsigned short*)(ws + (3u << 21) + (1u << 25));
    const size_t FN = (size_t)CD * NT * DD;   // 2M
    const size_t WN = (size_t)DD * DD / 1;    // 1M per W matrix
    unsigned short* Fh  = sp;
    unsigned short* Fm  = Fh + FN;
    unsigned short* Fl  = Fm + FN;
    unsigned short* WQh = Fl + FN;
    unsigned short* WQm = WQh + WN;
    unsigned short* WQl = WQm + WN;
    unsigned short* WKh = WQl + WN;
    unsigned short* WKm = WKh + WN;
    unsigned short* WKl = WKm + WN;
    unsigned short* WCh = WKl + WN;
    unsigned short* WCm = WCh + WN;
    unsigned short* WCl = WCm + WN;

    k0_split<<<dim3(512, 4), 256, 0, stream>>>(f_a, WQw, WKw, Cw,
        Fh, Fm, Fl, WQh, WQm, WQl, WKh, WKm, WKl, WCh, WCm, WCl);
    k1_mfma<<<dim3(16, 16, 3), 256, 0, stream>>>(
        Fh, Fm, Fl, WQh, WQm, WQl, WKh, WKm, WKl, WCh, WCm, WCl,
        WQb, WKb, Cb, Q, Kp, V);
    k2a_aff<<<dim3(16, 16, 32), 256, 0, stream>>>(Q, Kp, aff);
    k3_scan<<<dim3(4, 128, 2), 256, 0, stream>>>(pe, iou, WGw, WGb, aff, cv, ci);
    k2b2_fin<<<8192, 256, 0, stream>>>(cv, ci, V, yout);
}

// Round 12
// 410.511 us; speedup vs baseline: 1.3052x; 1.0385x over previous
//
#include <hip/hip_runtime.h>
#include <math.h>

#define NT 1024
#define CD 2
#define DD 1024
#define GG 16
#define LOG1E6 -13.8155105579642740f
#define NEG_BIG -1e30f

typedef short bf16x8 __attribute__((ext_vector_type(8)));
typedef float f32x4  __attribute__((ext_vector_type(4)));

__device__ __forceinline__ unsigned short bf16_rne(float x) {
    unsigned int u = __float_as_uint(x);
    unsigned int r = (u + 0x7fffu + ((u >> 16) & 1u)) >> 16;
    return (unsigned short)r;
}

__device__ __forceinline__ void split3_8(const float* v, bf16x8& h, bf16x8& m, bf16x8& l) {
    #pragma unroll
    for (int e = 0; e < 8; ++e) {
        const float x = v[e];
        const unsigned short hb = bf16_rne(x);
        const float hf = __uint_as_float((unsigned int)hb << 16);
        const float r1 = x - hf;
        const unsigned short mb = bf16_rne(r1);
        const float mf = __uint_as_float((unsigned int)mb << 16);
        const float r2 = r1 - mf;
        const unsigned short lb = bf16_rne(r2);
        h[e] = (short)hb; m[e] = (short)mb; l[e] = (short)lb;
    }
}

// ---------------------------------------------------------------------------
// K0: pre-split fa / Wq / Wk / Wc into exact 3-way bf16 (h+m+l) arrays.
// ---------------------------------------------------------------------------
__global__ __launch_bounds__(256) void k0_split(
    const float* __restrict__ fa, const float* __restrict__ Wq,
    const float* __restrict__ Wk, const float* __restrict__ Wc,
    unsigned short* __restrict__ Fh, unsigned short* __restrict__ Fm, unsigned short* __restrict__ Fl,
    unsigned short* __restrict__ WQh, unsigned short* __restrict__ WQm, unsigned short* __restrict__ WQl,
    unsigned short* __restrict__ WKh, unsigned short* __restrict__ WKm, unsigned short* __restrict__ WKl,
    unsigned short* __restrict__ WCh, unsigned short* __restrict__ WCm, unsigned short* __restrict__ WCl)
{
    const int reg = blockIdx.y;
    const float* src = (reg == 0) ? fa : (reg == 1) ? Wq : (reg == 2) ? Wk : Wc;
    unsigned short* dh = (reg == 0) ? Fh : (reg == 1) ? WQh : (reg == 2) ? WKh : WCh;
    unsigned short* dm = (reg == 0) ? Fm : (reg == 1) ? WQm : (reg == 2) ? WKm : WCm;
    unsigned short* dl = (reg == 0) ? Fl : (reg == 1) ? WQl : (reg == 2) ? WKl : WCl;
    const int nv = (reg == 0) ? (1 << 19) : (1 << 18);   // float4 count

    for (int v = blockIdx.x * 256 + threadIdx.x; v < nv; v += gridDim.x * 256) {
        float4 x4 = *(const float4*)&src[(size_t)v * 4];
        float xv[4] = {x4.x, x4.y, x4.z, x4.w};
        ushort4 h4, m4, l4;
        unsigned short hv[4], mv[4], lv[4];
        #pragma unroll
        for (int q = 0; q < 4; ++q) {
            const float x = xv[q];
            const unsigned short hb = bf16_rne(x);
            const float hf = __uint_as_float((unsigned int)hb << 16);
            const float r1 = x - hf;
            const unsigned short mb = bf16_rne(r1);
            const float mf = __uint_as_float((unsigned int)mb << 16);
            const unsigned short lb = bf16_rne(r1 - mf);
            hv[q] = hb; mv[q] = mb; lv[q] = lb;
        }
        h4.x = hv[0]; h4.y = hv[1]; h4.z = hv[2]; h4.w = hv[3];
        m4.x = mv[0]; m4.y = mv[1]; m4.z = mv[2]; m4.w = mv[3];
        l4.x = lv[0]; l4.y = lv[1]; l4.z = lv[2]; l4.w = lv[3];
        *(ushort4*)&dh[(size_t)v * 4] = h4;
        *(ushort4*)&dm[(size_t)v * 4] = m4;
        *(ushort4*)&dl[(size_t)v * 4] = l4;
    }
}

// ---------------------------------------------------------------------------
// K1 v3: MFMA GEMM (6-term, R9/R11-validated).  z==2 -> fp32 V out.
//   z in {0,1} -> writes 3-way-split Q/K (h/m/l) for k2a_mfma; fp32 Q/K
//   are never materialized (nothing reads them).
// ---------------------------------------------------------------------------
__global__ __launch_bounds__(256) void k1_mfma(
    const unsigned short* __restrict__ Fh, const unsigned short* __restrict__ Fm,
    const unsigned short* __restrict__ Fl,
    const unsigned short* __restrict__ WQh, const unsigned short* __restrict__ WQm,
    const unsigned short* __restrict__ WQl,
    const unsigned short* __restrict__ WKh, const unsigned short* __restrict__ WKm,
    const unsigned short* __restrict__ WKl,
    const unsigned short* __restrict__ WCh, const unsigned short* __restrict__ WCm,
    const unsigned short* __restrict__ WCl,
    const float* __restrict__ bq, const float* __restrict__ bk, const float* __restrict__ bc,
    float* __restrict__ Vo,
    unsigned short* __restrict__ QSh, unsigned short* __restrict__ QSm, unsigned short* __restrict__ QSl,
    unsigned short* __restrict__ KSh, unsigned short* __restrict__ KSm, unsigned short* __restrict__ KSl)
{
    const int et = blockIdx.x, rt = blockIdx.y, z = blockIdx.z;
    const unsigned short* Wh = (z == 0) ? WQh : (z == 1) ? WKh : WCh;
    const unsigned short* Wm = (z == 0) ? WQm : (z == 1) ? WKm : WCm;
    const unsigned short* Wl = (z == 0) ? WQl : (z == 1) ? WKl : WCl;
    const float* bb = (z == 0) ? bq : (z == 1) ? bk : bc;
    unsigned short* Sh = (z == 0) ? QSh : KSh;
    unsigned short* Sm = (z == 0) ? QSm : KSm;
    unsigned short* Sl = (z == 0) ? QSl : KSl;

    const int c  = rt >> 3;
    const int n0 = (rt & 7) * 128;
    const int r0 = rt * 128;
    const int e0 = et * 64;

    __shared__ unsigned short Ah[128][36], Am[128][36], Al[128][36];
    __shared__ unsigned short Bh[64][36],  Bm[64][36],  Bl[64][36];

    const int t    = threadIdx.x;
    const int wave = t >> 6, lane = t & 63;
    const int wr   = wave >> 1, wc = wave & 1;
    const int lrow = lane & 15, lk = lane >> 4;

    f32x4 acc[4][2];
    #pragma unroll
    for (int m = 0; m < 4; ++m)
        #pragma unroll
        for (int n = 0; n < 2; ++n) acc[m][n] = (f32x4){0.f, 0.f, 0.f, 0.f};

    for (int kt = 0; kt < 32; ++kt) {
        const int kb = kt * 32;
        #pragma unroll
        for (int p = 0; p < 2; ++p) {
            const int task = t + p * 256;
            const int row = task >> 2, seg = task & 3;
            const size_t gs = ((size_t)((n0 + row) * CD + c)) * DD + kb + seg * 8;
            *(uint4*)&Ah[row][seg * 8] = *(const uint4*)&Fh[gs];
            *(uint4*)&Am[row][seg * 8] = *(const uint4*)&Fm[gs];
            *(uint4*)&Al[row][seg * 8] = *(const uint4*)&Fl[gs];
        }
        {
            const int row = t >> 2, seg = t & 3;
            const size_t gs = ((size_t)(e0 + row)) * DD + kb + seg * 8;
            *(uint4*)&Bh[row][seg * 8] = *(const uint4*)&Wh[gs];
            *(uint4*)&Bm[row][seg * 8] = *(const uint4*)&Wm[gs];
            *(uint4*)&Bl[row][seg * 8] = *(const uint4*)&Wl[gs];
        }
        __syncthreads();
        {
            bf16x8 ah[4], am[4], al[4], bh[2], bm[2], bl[2];
            #pragma unroll
            for (int m = 0; m < 4; ++m) {
                const int row = wr * 64 + m * 16 + lrow;
                ah[m] = *(const bf16x8*)&Ah[row][lk * 8];
                am[m] = *(const bf16x8*)&Am[row][lk * 8];
                al[m] = *(const bf16x8*)&Al[row][lk * 8];
            }
            #pragma unroll
            for (int n = 0; n < 2; ++n) {
                const int row = wc * 32 + n * 16 + lrow;
                bh[n] = *(const bf16x8*)&Bh[row][lk * 8];
                bm[n] = *(const bf16x8*)&Bm[row][lk * 8];
                bl[n] = *(const bf16x8*)&Bl[row][lk * 8];
            }
            #pragma unroll
            for (int m = 0; m < 4; ++m)
                #pragma unroll
                for (int n = 0; n < 2; ++n) {
                    acc[m][n] = __builtin_amdgcn_mfma_f32_16x16x32_bf16(al[m], bh[n], acc[m][n], 0, 0, 0);
                    acc[m][n] = __builtin_amdgcn_mfma_f32_16x16x32_bf16(ah[m], bl[n], acc[m][n], 0, 0, 0);
                    acc[m][n] = __builtin_amdgcn_mfma_f32_16x16x32_bf16(am[m], bm[n], acc[m][n], 0, 0, 0);
                    acc[m][n] = __builtin_amdgcn_mfma_f32_16x16x32_bf16(am[m], bh[n], acc[m][n], 0, 0, 0);
                    acc[m][n] = __builtin_amdgcn_mfma_f32_16x16x32_bf16(ah[m], bm[n], acc[m][n], 0, 0, 0);
                    acc[m][n] = __builtin_amdgcn_mfma_f32_16x16x32_bf16(ah[m], bh[n], acc[m][n], 0, 0, 0);
                }
        }
        __syncthreads();
    }
    // epilogue: C frag row=(lk*4+q) -> output row; col=lrow -> e  [m89]
    #pragma unroll
    for (int n = 0; n < 2; ++n) {
        const int e = e0 + wc * 32 + n * 16 + lrow;
        const float bias = bb[e];
        #pragma unroll
        for (int m = 0; m < 4; ++m) {
            const int r = r0 + wr * 64 + m * 16 + lk * 4;
            #pragma unroll
            for (int q = 0; q < 4; ++q) {
                const float val = acc[m][n][q] + bias;
                const size_t idx = ((size_t)(r + q)) * DD + e;
                if (z == 2) {
                    Vo[idx] = val;
                } else {
                    const unsigned short hb = bf16_rne(val);
                    const float hf = __uint_as_float((unsigned int)hb << 16);
                    const float r1 = val - hf;
                    const unsigned short mb = bf16_rne(r1);
                    const float mf = __uint_as_float((unsigned int)mb << 16);
                    const unsigned short lb = bf16_rne(r1 - mf);
                    Sh[idx] = hb; Sm[idx] = mb; Sl[idx] = lb;
                }
            }
        }
    }
}

// ---------------------------------------------------------------------------
// K2a v3: aff = Q.K^T/8 on the MATRIX pipe, rebuilt on the R11 k1 pattern
//   (R10's failure was structure: 170 VGPR + 1 dep chain; precision was
//   proven fine - R10 passed at 0.00390625).
//   Block = 64i x 64j tile of one (c,g); LDS 6x[64][36] ushort = 27.6KB
//   (5 blocks/CU); BK=32 x 2 k-steps; 4 waves (2x2), 4 indep acc chains;
//   staging = pure uint4 copies.  Q/K slices per (c,g) = 384KB -> L2-hot.
// ---------------------------------------------------------------------------
__global__ __launch_bounds__(256) void k2a_mfma(
    const unsigned short* __restrict__ QSh, const unsigned short* __restrict__ QSm,
    const unsigned short* __restrict__ QSl,
    const unsigned short* __restrict__ KSh, const unsigned short* __restrict__ KSm,
    const unsigned short* __restrict__ KSl,
    float* __restrict__ aff)
{
    const int jt = blockIdx.x, it = blockIdx.y, cg = blockIdx.z;
    const int c = cg >> 4, g = cg & 15;
    const int i0 = it * 64, j0 = jt * 64;

    __shared__ unsigned short Qh[64][36], Qm[64][36], Ql[64][36];
    __shared__ unsigned short Kh[64][36], Km[64][36], Kl[64][36];

    const int t    = threadIdx.x;
    const int wave = t >> 6, lane = t & 63;
    const int wr   = wave >> 1, wc = wave & 1;
    const int lrow = lane & 15, lk = lane >> 4;

    f32x4 acc[2][2];
    #pragma unroll
    for (int m = 0; m < 2; ++m)
        #pragma unroll
        for (int n = 0; n < 2; ++n) acc[m][n] = (f32x4){0.f, 0.f, 0.f, 0.f};

    for (int kt = 0; kt < 2; ++kt) {
        const int kb = g * 64 + kt * 32;
        {
            const int row = t >> 2, seg = t & 3;
            const size_t qs = ((size_t)(c * NT + i0 + row)) * DD + kb + seg * 8;
            *(uint4*)&Qh[row][seg * 8] = *(const uint4*)&QSh[qs];
            *(uint4*)&Qm[row][seg * 8] = *(const uint4*)&QSm[qs];
            *(uint4*)&Ql[row][seg * 8] = *(const uint4*)&QSl[qs];
            const size_t ks = ((size_t)(c * NT + j0 + row)) * DD + kb + seg * 8;
            *(uint4*)&Kh[row][seg * 8] = *(const uint4*)&KSh[ks];
            *(uint4*)&Km[row][seg * 8] = *(const uint4*)&KSm[ks];
            *(uint4*)&Kl[row][seg * 8] = *(const uint4*)&KSl[ks];
        }
        __syncthreads();
        {
            bf16x8 qh[2], qm[2], ql[2], kh[2], km[2], kl[2];
            #pragma unroll
            for (int m = 0; m < 2; ++m) {
                const int row = wr * 32 + m * 16 + lrow;
                qh[m] = *(const bf16x8*)&Qh[row][lk * 8];
                qm[m] = *(const bf16x8*)&Qm[row][lk * 8];
                ql[m] = *(const bf16x8*)&Ql[row][lk * 8];
            }
            #pragma unroll
            for (int n = 0; n < 2; ++n) {
                const int row = wc * 32 + n * 16 + lrow;
                kh[n] = *(const bf16x8*)&Kh[row][lk * 8];
                km[n] = *(const bf16x8*)&Km[row][lk * 8];
                kl[n] = *(const bf16x8*)&Kl[row][lk * 8];
            }
            #pragma unroll
            for (int m = 0; m < 2; ++m)
                #pragma unroll
                for (int n = 0; n < 2; ++n) {
                    acc[m][n] = __builtin_amdgcn_mfma_f32_16x16x32_bf16(ql[m], kh[n], acc[m][n], 0, 0, 0);
                    acc[m][n] = __builtin_amdgcn_mfma_f32_16x16x32_bf16(qh[m], kl[n], acc[m][n], 0, 0, 0);
                    acc[m][n] = __builtin_amdgcn_mfma_f32_16x16x32_bf16(qm[m], km[n], acc[m][n], 0, 0, 0);
                    acc[m][n] = __builtin_amdgcn_mfma_f32_16x16x32_bf16(qm[m], kh[n], acc[m][n], 0, 0, 0);
                    acc[m][n] = __builtin_amdgcn_mfma_f32_16x16x32_bf16(qh[m], km[n], acc[m][n], 0, 0, 0);
                    acc[m][n] = __builtin_amdgcn_mfma_f32_16x16x32_bf16(qh[m], kh[n], acc[m][n], 0, 0, 0);
                }
        }
        __syncthreads();
    }
    // C frag: row=(lk*4+q) -> i ; col=lrow -> j  [m89]
    #pragma unroll
    for (int m = 0; m < 2; ++m) {
        const int i = i0 + wr * 32 + m * 16 + lk * 4;
        #pragma unroll
        for (int n = 0; n < 2; ++n) {
            const int j = j0 + wc * 32 + n * 16 + lrow;
            #pragma unroll
            for (int q = 0; q < 4; ++q)
                aff[((size_t)cg * NT + i + q) * NT + j] = acc[m][n][q] * 0.125f;
        }
    }
}

// ---------------------------------------------------------------------------
// K3 (unchanged from R9): fused dense + top-10 scan; phase-G on MFMA.
// ---------------------------------------------------------------------------
__global__ __launch_bounds__(256, 4) void k3_scan(
    const float* __restrict__ pe, const float* __restrict__ iou,
    const float* __restrict__ WGw, const float* __restrict__ WGb,
    const float* __restrict__ aff,
    float* __restrict__ cv, int* __restrict__ ci)
{
    const int ch = blockIdx.x;
    const int it = blockIdx.y;
    const int c  = blockIdx.z;
    const int i0 = it * 8;

    __shared__ float wgl[8][16][33];
    __shared__ float ios[8][33];

    const int t = threadIdx.x;
    const int wave = t >> 6, lane = t & 63;
    const int lg = lane & 15, lk = lane >> 4;
    const int p_i = t >> 5, jq = t & 31;
    const int s_i = t >> 5, s_g = (t >> 1) & 15, s_h = t & 1;

    bf16x8 bh[2], bm[2], bl[2];
    #pragma unroll
    for (int kp = 0; kp < 2; ++kp) {
        float w8[8];
        float4 w0 = *(const float4*)&WGw[lg * 64 + kp * 32 + lk * 8];
        float4 w1 = *(const float4*)&WGw[lg * 64 + kp * 32 + lk * 8 + 4];
        w8[0]=w0.x; w8[1]=w0.y; w8[2]=w0.z; w8[3]=w0.w;
        w8[4]=w1.x; w8[5]=w1.y; w8[6]=w1.z; w8[7]=w1.w;
        split3_8(w8, bh[kp], bm[kp], bl[kp]);
    }
    const float bias = WGb[lg];

    float tv[10]; int tidx[10];
    #pragma unroll
    for (int q = 0; q < 10; ++q) { tv[q] = NEG_BIG; tidx[q] = 0; }

    for (int s = 0; s < 8; ++s) {
        const int j0 = ch * 256 + s * 32;
        {
            const float ia = iou[((size_t)c * NT + (i0 + p_i)) * NT + j0 + jq];
            ios[p_i][jq] = (ia >= 1e-6f) ? 0.f : LOG1E6;
        }
        #pragma unroll 1
        for (int rtt = 0; rtt < 4; ++rtt) {
            const int rt = wave * 4 + rtt;
            const int ib = rt >> 1;
            const int jb = (rt & 1) * 16;
            const float* pr = &pe[(((size_t)c * NT + (i0 + ib)) * NT + (j0 + jb + lg)) * 64];
            f32x4 acc = {0.f, 0.f, 0.f, 0.f};
            #pragma unroll
            for (int kp = 0; kp < 2; ++kp) {
                float a8[8];
                float4 v0 = *(const float4*)&pr[kp * 32 + lk * 8];
                float4 v1 = *(const float4*)&pr[kp * 32 + lk * 8 + 4];
                a8[0]=v0.x; a8[1]=v0.y; a8[2]=v0.z; a8[3]=v0.w;
                a8[4]=v1.x; a8[5]=v1.y; a8[6]=v1.z; a8[7]=v1.w;
                bf16x8 ah, am, al;
                split3_8(a8, ah, am, al);
                acc = __builtin_amdgcn_mfma_f32_16x16x32_bf16(al, bh[kp], acc, 0, 0, 0);
                acc = __builtin_amdgcn_mfma_f32_16x16x32_bf16(ah, bl[kp], acc, 0, 0, 0);
                acc = __builtin_amdgcn_mfma_f32_16x16x32_bf16(am, bm[kp], acc, 0, 0, 0);
                acc = __builtin_amdgcn_mfma_f32_16x16x32_bf16(am, bh[kp], acc, 0, 0, 0);
                acc = __builtin_amdgcn_mfma_f32_16x16x32_bf16(ah, bm[kp], acc, 0, 0, 0);
                acc = __builtin_amdgcn_mfma_f32_16x16x32_bf16(ah, bh[kp], acc, 0, 0, 0);
            }
            #pragma unroll
            for (int q = 0; q < 4; ++q) {
                const float v = acc[q] + bias;
                wgl[ib][lg][jb + lk * 4 + q] = (v > 1e-6f) ? __logf(v) : LOG1E6;
            }
        }
        __syncthreads();
        {
            const float* ar = &aff[(((size_t)(c * GG + s_g)) * NT + (i0 + s_i)) * NT + j0 + s_h * 16];
            const float* wl = &wgl[s_i][s_g][s_h * 16];
            const float* il = &ios[s_i][s_h * 16];
            #pragma unroll
            for (int j4 = 0; j4 < 16; j4 += 4) {
                float4 a4 = *(const float4*)&ar[j4];
                float av[4] = {a4.x, a4.y, a4.z, a4.w};
                #pragma unroll
                for (int q = 0; q < 4; ++q) {
                    const float val = wl[j4 + q] + av[q] + il[j4 + q];
                    if (val > tv[0]) {
                        const int ix = j0 + s_h * 16 + j4 + q;
                        #pragma unroll
                        for (int sl = 0; sl < 10; ++sl) {
                            const bool up   = (sl < 9) ? (val > tv[sl + 1]) : false;
                            const bool here = (val > tv[sl]);
                            const float ntv = up ? tv[sl + 1] : (here ? val : tv[sl]);
                            const int   nti = up ? tidx[sl + 1] : (here ? ix : tidx[sl]);
                            tv[sl] = ntv; tidx[sl] = nti;
                        }
                    }
                }
            }
        }
        __syncthreads();
    }

    float* mv = &wgl[0][0][0];
    int*   mi = (int*)(mv + 1280);
    const int pair = t >> 1;
    if (s_h == 1) {
        #pragma unroll
        for (int q = 0; q < 10; ++q) { mv[pair * 10 + q] = tv[q]; mi[pair * 10 + q] = tidx[q]; }
    }
    __syncthreads();
    if (s_h == 0) {
        for (int q = 9; q >= 0; --q) {
            const float val = mv[pair * 10 + q];
            const int   ix  = mi[pair * 10 + q];
            if (val > tv[0]) {
                #pragma unroll
                for (int sl = 0; sl < 10; ++sl) {
                    const bool up   = (sl < 9) ? (val > tv[sl + 1]) : false;
                    const bool here = (val > tv[sl]);
                    const float ntv = up ? tv[sl + 1] : (here ? val : tv[sl]);
                    const int   nti = up ? tidx[sl + 1] : (here ? ix : tidx[sl]);
                    tv[sl] = ntv; tidx[sl] = nti;
                }
            }
        }
        const size_t base = ((((size_t)c * NT + (i0 + s_i)) * GG + s_g) * 4 + ch) * 10;
        #pragma unroll
        for (int q = 0; q < 10; ++q) { cv[base + q] = tv[q]; ci[base + q] = tidx[q]; }
    }
}

// ---------------------------------------------------------------------------
// K2b2 (unchanged): per-(c,i,g) wave merge + softmax + coalesced V-gather.
// ---------------------------------------------------------------------------
__global__ __launch_bounds__(256) void k2b2_fin(
    const float* __restrict__ cv, const int* __restrict__ ci,
    const float* __restrict__ V, float* __restrict__ y)
{
    const int w    = (blockIdx.x << 2) + (threadIdx.x >> 6);
    const int lane = threadIdx.x & 63;
    const int c = w >> 14;
    const int i = (w >> 4) & (NT - 1);
    const int g = w & 15;

    float tv[10]; int tidx[10];
    #pragma unroll
    for (int q = 0; q < 10; ++q) { tv[q] = NEG_BIG; tidx[q] = 0; }

    const size_t base = (size_t)w * 40;
    for (int chn = 0; chn < 4; ++chn) {
        const float* cvp = &cv[base + chn * 10];
        const int*   cip = &ci[base + chn * 10];
        for (int q = 9; q >= 0; --q) {
            const float val = cvp[q];
            const int   ix  = cip[q];
            if (val > tv[0]) {
                #pragma unroll
                for (int sl = 0; sl < 10; ++sl) {
                    const bool up   = (sl < 9) ? (val > tv[sl + 1]) : false;
                    const bool here = (val > tv[sl]);
                    const float ntv = up ? tv[sl + 1] : (here ? val : tv[sl]);
                    const int   nti = up ? tidx[sl + 1] : (here ? ix : tidx[sl]);
                    tv[sl] = ntv; tidx[sl] = nti;
                }
            }
        }
    }
    const float m = tv[9];
    float wgt[10]; float sm = 0.f;
    #pragma unroll
    for (int q = 0; q < 10; ++q) { wgt[q] = __expf(tv[q] - m); sm += wgt[q]; }
    const float inv = 1.f / sm;
    float o = 0.f;
    #pragma unroll
    for (int q = 0; q < 10; ++q)
        o += (wgt[q] * inv) * V[((size_t)(c * NT + tidx[q])) * DD + g * 64 + lane];
    y[((size_t)i * CD + c) * DD + g * 64 + lane] = o;
}

extern "C" void kernel_launch(void* const* d_in, const int* in_sizes, int n_in,
                              void* d_out, int out_size, void* d_ws, size_t ws_size,
                              hipStream_t stream) {
    (void)in_sizes; (void)n_in; (void)out_size; (void)ws_size;
    const float* f_a = (const float*)d_in[0];
    const float* pe  = (const float*)d_in[1];
    const float* iou = (const float*)d_in[2];
    const float* WGw = (const float*)d_in[3];
    const float* WGb = (const float*)d_in[4];
    const float* WKw = (const float*)d_in[5];
    const float* WKb = (const float*)d_in[6];
    const float* WQw = (const float*)d_in[7];
    const float* WQb = (const float*)d_in[8];
    const float* Cw  = (const float*)d_in[9];
    const float* Cb  = (const float*)d_in[10];
    float* yout = (float*)d_out;

    // ws floats: cv [0..2^21) | ci [2^21..2^22) | V [2^22..3*2^21) |
    //   aff [3*2^21 .. +2^25) | then ushort arrays: k0 splits (15M) +
    //   Q/K splits (12M).  Total ~212MB.
    float* ws  = (float*)d_ws;
    float* V   = ws + (2u << 21);
    float* aff = ws + (3u << 21);
    float* cv  = ws;
    int*   ci  = (int*)(ws + (1u << 21));
    unsigned short* sp = (unsigned short*)(ws + (3u << 21) + (1u << 25));
    const size_t FN = (size_t)CD * NT * DD;   // 2M
    const size_t WN = (size_t)DD * DD;        // 1M
    unsigned short* Fh  = sp;
    unsigned short* Fm  = Fh + FN;
    unsigned short* Fl  = Fm + FN;
    unsigned short* WQh = Fl + FN;
    unsigned short* WQm = WQh + WN;
    unsigned short* WQl = WQm + WN;
    unsigned short* WKh = WQl + WN;
    unsigned short* WKm = WKh + WN;
    unsigned short* WKl = WKm + WN;
    unsigned short* WCh = WKl + WN;
    unsigned short* WCm = WCh + WN;
    unsigned short* WCl = WCm + WN;
    unsigned short* QSh = WCl + WN;
    unsigned short* QSm = QSh + FN;
    unsigned short* QSl = QSm + FN;
    unsigned short* KSh = QSl + FN;
    unsigned short* KSm = KSh + FN;
    unsigned short* KSl = KSm + FN;

    k0_split<<<dim3(512, 4), 256, 0, stream>>>(f_a, WQw, WKw, Cw,
        Fh, Fm, Fl, WQh, WQm, WQl, WKh, WKm, WKl, WCh, WCm, WCl);
    k1_mfma<<<dim3(16, 16, 3), 256, 0, stream>>>(
        Fh, Fm, Fl, WQh, WQm, WQl, WKh, WKm, WKl, WCh, WCm, WCl,
        WQb, WKb, Cb, V, QSh, QSm, QSl, KSh, KSm, KSl);
    k2a_mfma<<<dim3(16, 16, 32), 256, 0, stream>>>(QSh, QSm, QSl, KSh, KSm, KSl, aff);
    k3_scan<<<dim3(4, 128, 2), 256, 0, stream>>>(pe, iou, WGw, WGb, aff, cv, ci);
    k2b2_fin<<<8192, 256, 0, stream>>>(cv, ci, V, yout);
}